// Round 1
// baseline (172.658 us; speedup 1.0000x reference)
//
#include <hip/hip_runtime.h>
#include <math.h>

// MCPBRNN scalar recurrence, B=100000 steps, H=1.
// Strategy: chunked speculative scan. State map is contracting (|df/dc| <~ 0.9),
// so each 64-step chunk is recovered exactly (to fp noise) by a 512-step
// warm-up from c=0 starting at s0-512. 1563 independent threads.

#define SPIN  365
#define TRAIN 5000
#define CHUNK 64
#define WARM  512
#define PF    8      // load-pipeline depth (steps prefetched ahead)

#define MLc 2.9086f
#define SLc 1.898f

__device__ __forceinline__ float exp2a(float x) {  // v_exp_f32: 2^x
    float r; asm("v_exp_f32 %0, %1" : "=v"(r) : "v"(x)); return r;
}
__device__ __forceinline__ float rcpa(float x) {   // v_rcp_f32: ~1ulp 1/x
    float r; asm("v_rcp_f32 %0, %1" : "=v"(r) : "v"(x)); return r;
}

// ---- obs_std = std(y[SPIN:TRAIN], ddof=1), double accumulation ----
__global__ void std_kernel(const float* __restrict__ y, float* __restrict__ stdp) {
    __shared__ double s1[256], s2[256];
    const int t = threadIdx.x;
    double a = 0.0, b = 0.0;
    for (int i = SPIN + t; i < TRAIN; i += 256) {
        double v = (double)y[i];
        a += v; b += v * v;
    }
    s1[t] = a; s2[t] = b;
    __syncthreads();
    for (int w = 128; w > 0; w >>= 1) {
        if (t < w) { s1[t] += s1[t + w]; s2[t] += s2[t + w]; }
        __syncthreads();
    }
    if (t == 0) {
        const double n = (double)(TRAIN - SPIN);
        const double var = (s2[0] - s1[0] * s1[0] / n) / (n - 1.0);
        *stdp = (float)sqrt(var);
    }
}

// ---- constant / zero outputs: bp_n, g_ib, obs_std, h_nout[:,1], tl-prefix rows ----
__global__ void fill_kernel(float* __restrict__ out, int B,
                            const float* __restrict__ stdp,
                            const int* __restrict__ tlp) {
    const float s = *stdp;
    const int tl = *tlp;
    const int i = blockIdx.x * blockDim.x + threadIdx.x;
    if (i >= B) return;
    const float m = (i < tl) ? 0.0f : s;
    out[4 * B + i] = 0.0f;          // bp_n
    out[6 * B + i] = 0.0f;          // g_ib
    out[12 * B + 2 * i + 1] = m;    // h_nout[:,1]
    out[14 * B + i] = m;            // obs_std
    if (i < tl) {                   // rows skipped by the scan are zero
        out[i] = 0.0f;              out[B + i] = 0.0f;
        out[2 * B + i] = 0.0f;      out[3 * B + i] = 0.0f;
        out[5 * B + i] = 0.0f;      out[7 * B + i] = 0.0f;
        out[8 * B + i] = 0.0f;      out[9 * B + i] = 0.0f;
        out[10 * B + i] = 0.0f;     out[11 * B + i] = 0.0f;
        out[12 * B + 2 * i] = 0.0f; // h_nout[:,0]
    }
}

// ---- the scan ----
__global__ void scan_kernel(const float* __restrict__ x,
                            const float* __restrict__ p_mean,
                            const float* __restrict__ p_std,
                            const float* __restrict__ w_r_yom,
                            const float* __restrict__ w_r_yom_gw,
                            const float* __restrict__ w_r_ylm,
                            const float* __restrict__ w_r_yfm,
                            const float* __restrict__ b0_yom,
                            const float* __restrict__ w_b1_yom,
                            const float* __restrict__ b0_yom_gw,
                            const float* __restrict__ w_b1_yom_gw,
                            const float* __restrict__ b0_ylm,
                            const float* __restrict__ w_b2_ylm,
                            const int* __restrict__ tlp,
                            float* __restrict__ out, int B) {
    const int tid = blockIdx.x * blockDim.x + threadIdx.x;
    const int tl = *tlp;
    const int N = B - tl;                 // number of scan steps
    const int s0 = tid * CHUNK;           // first emitted step of this chunk
    if (s0 >= N) return;
    const int send = min(s0 + CHUNK, N);
    const int ws = max(0, s0 - WARM);     // warm-up start (exact init when ws==0)
    const int W0 = s0 - ws;               // warm-up count: multiple of PF by construction

    // ---- hoist all step-independent scalar math ----
    const float pm = p_mean[0], ps = p_std[0];
    const float inv_ps = 1.0f / ps;
    const float ea = __expf(w_r_yom[0]);
    const float eb = __expf(w_r_yom_gw[0]);
    const float ec = __expf(w_r_ylm[0]);
    const float ed = __expf(w_r_yfm[0]);
    const float iden = 1.0f / (ea + eb + ec + ed);
    const float oo1 = ea * iden, oogw1 = eb * iden, ol1 = ec * iden;
    const float LOG2E = 1.4426950408889634f;
    // sigmoid(k + c*m) = 1/(1 + exp2(A + c*M)),  A=-k*log2e, M=-m*log2e
    const float m1 = w_b1_yom[0]    * inv_ps, k1 = b0_yom[0]    - pm * m1;
    const float m2 = w_b1_yom_gw[0] * inv_ps, k2 = b0_yom_gw[0] - pm * m2;
    const float m3 = w_b2_ylm[0] * (1.0f / SLc), k3 = b0_ylm[0] - MLc * m3;
    const float A1 = -k1 * LOG2E, M1 = -m1 * LOG2E;
    const float A2 = -k2 * LOG2E, M2 = -m2 * LOG2E;
    const float A3 = -k3 * LOG2E, M3 = -m3 * LOG2E;

    float* o_h    = out;
    float* o_c    = out + 1  * (size_t)B;
    float* o_l    = out + 2  * (size_t)B;
    float* o_lc   = out + 3  * (size_t)B;
    float* o_gw   = out + 5  * (size_t)B;
    float* o_goo  = out + 7  * (size_t)B;
    float* o_gol  = out + 8  * (size_t)B;
    float* o_golc = out + 9  * (size_t)B;
    float* o_gf   = out + 10 * (size_t)B;
    float* o_gogw = out + 11 * (size_t)B;
    float* o_hno  = out + 12 * (size_t)B;

    const float2* xp = (const float2*)x + tl;   // step j reads xp[j] = (u1,u2)
    const int Nm1 = N - 1;

    float c = 0.0f;
    float2 buf[PF];                             // static-indexed ring (stays in VGPRs)
#pragma unroll
    for (int d = 0; d < PF; ++d) buf[d] = xp[min(ws + d, Nm1)];

    // ---- warm-up: advance state only ----
    for (int i = 0; i < W0; i += PF) {
#pragma unroll
        for (int d = 0; d < PF; ++d) {
            const float2 u = buf[d];
            buf[d] = xp[min(ws + i + PF + d, Nm1)];   // prefetch PF steps ahead
            const float ol   = ol1   * rcpa(1.0f + exp2a(fmaf(u.y, M3, A3)));
            const float r1   =         rcpa(1.0f + exp2a(fmaf(c,   M1, A1)));
            const float oogw = oogw1 * rcpa(1.0f + exp2a(fmaf(c,   M2, A2)));
            const float q    = u.y * rcpa(c);
            const float olc  = (c > 0.0f) ? fminf(ol, q) : ol;
            const float s    = fmaf(oo1, r1, oogw) + olc;   // oo+oogw+olc
            c = fmaf(-s, c, c + u.x);                       // c*(1-s) + u1
        }
    }

    // ---- emit: advance state + write the 11 per-step outputs ----
    for (int i = 0; i < CHUNK; i += PF) {
#pragma unroll
        for (int d = 0; d < PF; ++d) {
            const int j = s0 + i + d;
            const float2 u = buf[d];
            buf[d] = xp[min(s0 + i + PF + d, Nm1)];
            const float ol   = ol1   * rcpa(1.0f + exp2a(fmaf(u.y, M3, A3)));
            const float oo   = oo1   * rcpa(1.0f + exp2a(fmaf(c,   M1, A1)));
            const float oogw = oogw1 * rcpa(1.0f + exp2a(fmaf(c,   M2, A2)));
            const float q    = u.y * rcpa(c);
            const float olc  = (c > 0.0f) ? fminf(ol, q) : ol;
            const float s    = (oo + oogw) + olc;
            const float f    = 1.0f - s;
            if (j < send) {
                const int b = tl + j;
                const float h = oo * c;
                o_h[b]    = h;
                o_c[b]    = c;
                o_l[b]    = ol * c;
                o_lc[b]   = olc * c;
                o_gw[b]   = oogw * c;
                o_goo[b]  = oo;
                o_gol[b]  = ol;
                o_golc[b] = olc;
                o_gf[b]   = f;
                o_gogw[b] = oogw;
                o_hno[2 * (size_t)b] = h;       // h_nout[:,0]
            }
            c = fmaf(-s, c, c + u.x);
        }
    }
}

extern "C" void kernel_launch(void* const* d_in, const int* in_sizes, int n_in,
                              void* d_out, int out_size, void* d_ws, size_t ws_size,
                              hipStream_t stream) {
    const float* x          = (const float*)d_in[0];
    const float* y_obs      = (const float*)d_in[1];
    const float* p_mean     = (const float*)d_in[2];
    const float* p_std      = (const float*)d_in[3];
    const float* w_r_yom    = (const float*)d_in[4];
    const float* w_r_yom_gw = (const float*)d_in[5];
    const float* w_r_ylm    = (const float*)d_in[6];
    const float* w_r_yfm    = (const float*)d_in[7];
    const float* b0_yom     = (const float*)d_in[8];
    const float* w_b1_yom   = (const float*)d_in[9];
    const float* b0_yom_gw  = (const float*)d_in[10];
    const float* w_b1_yomgw = (const float*)d_in[11];
    const float* b0_ylm     = (const float*)d_in[12];
    const float* w_b2_ylm   = (const float*)d_in[13];
    // d_in[14] = epoch (unused by the reference)
    const int*   tlp        = (const int*)d_in[15];

    float* out  = (float*)d_out;
    float* stdp = (float*)d_ws;          // 4 bytes of scratch for obs_std
    const int B = in_sizes[1];           // y_obs has B elements

    hipLaunchKernelGGL(std_kernel, dim3(1), dim3(256), 0, stream, y_obs, stdp);
    hipLaunchKernelGGL(fill_kernel, dim3((B + 255) / 256), dim3(256), 0, stream,
                       out, B, stdp, tlp);

    const int nchunks = (B + CHUNK - 1) / CHUNK;
    hipLaunchKernelGGL(scan_kernel, dim3((nchunks + 255) / 256), dim3(256), 0, stream,
                       x, p_mean, p_std, w_r_yom, w_r_yom_gw, w_r_ylm, w_r_yfm,
                       b0_yom, w_b1_yom, b0_yom_gw, w_b1_yomgw, b0_ylm, w_b2_ylm,
                       tlp, out, B);
}

// Round 2
// 22.559 us; speedup vs baseline: 7.6538x; 7.6538x over previous
//
#include <hip/hip_runtime.h>
#include <math.h>

// MCPBRNN scalar recurrence, B=100000 steps, H=1.
// Chunked speculative scan (contraction lambda <= 0.89 -> WARM=96 gives ~8e-6
// init error, below the 0.0039 fp32 floor measured in round 1).
// Round-2 fix: round 1 was bound by the vector-memory address pipe (64 cache
// lines per wave access, ~700 line-transactions per emit step). Now all global
// traffic is coalesced: x staged block-contiguously into LDS (XOR-swizzled,
// conflict-free), outputs staged in LDS and flushed coalesced.

#define SPIN  365
#define TRAIN 5000
#define CHUNK 8
#define WARM  96
#define PF    4
#define BLK   128
#define SPAN  (BLK * CHUNK)      // 1024 emitted steps per block
#define TLEN  (SPAN + WARM)      // 1120 tile steps (max read idx 1119)

#define MLc 2.9086f
#define SLc 1.898f

__device__ __forceinline__ float exp2a(float x) {  // v_exp_f32: 2^x
    float r; asm("v_exp_f32 %0, %1" : "=v"(r) : "v"(x)); return r;
}
__device__ __forceinline__ float rcpa(float x) {   // v_rcp_f32: ~1ulp 1/x
    float r; asm("v_rcp_f32 %0, %1" : "=v"(r) : "v"(x)); return r;
}
// bank swizzle on a float index: XOR bits 0-4 with bits 3-7. Bijective within
// each 32-element (128 B) window; lanes reading at 8-element stride spread
// across all 32 banks (2 lanes/bank = free).
__device__ __forceinline__ int eswz(int e) { return e ^ ((e >> 3) & 31); }

// ---- std(y[SPIN:TRAIN], ddof=1) (redundant per block) + constant planes ----
__global__ void __launch_bounds__(256)
fill_kernel(const float* __restrict__ y, float* __restrict__ out, int B,
            const int* __restrict__ tlp) {
    __shared__ double s1[256], s2[256];
    const int t = threadIdx.x;
    double a = 0.0, q = 0.0;
    for (int k = SPIN + t; k < TRAIN; k += 256) {
        double v = (double)y[k]; a += v; q += v * v;
    }
    s1[t] = a; s2[t] = q;
    __syncthreads();
    for (int w = 128; w > 0; w >>= 1) {
        if (t < w) { s1[t] += s1[t + w]; s2[t] += s2[t + w]; }
        __syncthreads();
    }
    const double n = (double)(TRAIN - SPIN);
    const float sd = (float)sqrt((s2[0] - s1[0] * s1[0] / n) / (n - 1.0));

    const int tl = *tlp;
    const int i = blockIdx.x * 256 + t;
    if (i >= B) return;
    const size_t Bs = (size_t)B;
    const float m = (i < tl) ? 0.0f : sd;
    out[4 * Bs + i] = 0.0f;            // bp_n
    out[6 * Bs + i] = 0.0f;            // g_ib
    out[12 * Bs + 2 * (size_t)i + 1] = m;  // h_nout[:,1]
    out[14 * Bs + i] = m;              // obs_std
    if (i < tl) {                      // rows the scan skips are zero
        out[i] = 0.0f;           out[Bs + i] = 0.0f;
        out[2 * Bs + i] = 0.0f;  out[3 * Bs + i] = 0.0f;
        out[5 * Bs + i] = 0.0f;  out[7 * Bs + i] = 0.0f;
        out[8 * Bs + i] = 0.0f;  out[9 * Bs + i] = 0.0f;
        out[10 * Bs + i] = 0.0f; out[11 * Bs + i] = 0.0f;
        out[12 * Bs + 2 * (size_t)i] = 0.0f;
    }
}

// ---- the scan ----
__global__ void __launch_bounds__(BLK)
scan_kernel(const float* __restrict__ x,
            const float* __restrict__ p_mean, const float* __restrict__ p_std,
            const float* __restrict__ w_r_yom, const float* __restrict__ w_r_yom_gw,
            const float* __restrict__ w_r_ylm, const float* __restrict__ w_r_yfm,
            const float* __restrict__ b0_yom, const float* __restrict__ w_b1_yom,
            const float* __restrict__ b0_yom_gw, const float* __restrict__ w_b1_yom_gw,
            const float* __restrict__ b0_ylm, const float* __restrict__ w_b2_ylm,
            const int* __restrict__ tlp, float* __restrict__ out, int B) {
    __shared__ __align__(128) float tU1[TLEN], tOL[TLEN], tU2[TLEN];
    __shared__ __align__(128) float obuf[10 * SPAN];   // [plane][i][j]

    const int tl = *tlp;
    const int N = B - tl;
    if (N <= 0) return;                 // uniform exit, before any barrier

    // ---- step-independent scalar math ----
    const float pm = p_mean[0], inv_ps = 1.0f / p_std[0];
    const float ea = __expf(w_r_yom[0]);
    const float eb = __expf(w_r_yom_gw[0]);
    const float ec = __expf(w_r_ylm[0]);
    const float ed = __expf(w_r_yfm[0]);
    const float iden = 1.0f / (ea + eb + ec + ed);
    const float oo1 = ea * iden, oogw1 = eb * iden, ol1 = ec * iden;
    const float LOG2E = 1.4426950408889634f;
    const float m1 = w_b1_yom[0]    * inv_ps, k1 = b0_yom[0]    - pm * m1;
    const float m2 = w_b1_yom_gw[0] * inv_ps, k2 = b0_yom_gw[0] - pm * m2;
    const float m3 = w_b2_ylm[0] * (1.0f / SLc), k3 = b0_ylm[0] - MLc * m3;
    const float A1 = -k1 * LOG2E, M1 = -m1 * LOG2E;
    const float A2 = -k2 * LOG2E, M2 = -m2 * LOG2E;
    const float A3 = -k3 * LOG2E, M3 = -m3 * LOG2E;

    const int blkbase = blockIdx.x * SPAN;    // first emitted step of block
    const int T0 = blkbase - WARM;            // global step of tile slot 0
    const float2* xp = (const float2*)x + tl; // step g reads xp[g]

    // ---- stage x window into LDS (coalesced) + precompute ol(u2) ----
    for (int k = threadIdx.x; k < TLEN; k += BLK) {
        int g = T0 + k;
        g = min(max(g, 0), N - 1);
        const float2 u = xp[g];
        const float olv = ol1 * rcpa(1.0f + exp2a(fmaf(u.y, M3, A3)));
        const int ks = eswz(k);
        tU1[ks] = u.x; tOL[ks] = olv; tU2[ks] = u.y;
    }
    __syncthreads();

    const int i = threadIdx.x;
    const int s0g = blkbase + i * CHUNK;          // first emitted global step
    const int W0 = min(s0g, WARM);                // warm-up count (mult of 8)
    const int kw = i * CHUNK + (WARM - W0);       // first warm tile slot

    float c = 0.0f;
    float bu1[PF], bol[PF], bu2[PF];
#pragma unroll
    for (int d = 0; d < PF; ++d) {
        const int ks = eswz(kw + d);
        bu1[d] = tU1[ks]; bol[d] = tOL[ks]; bu2[d] = tU2[ks];
    }

    // ---- warm-up: state only, no division (olc*c == min(ol*c, u2)) ----
    for (int w = 0; w < W0; w += PF) {
#pragma unroll
        for (int d = 0; d < PF; ++d) {
            const float u1 = bu1[d], olv = bol[d], u2 = bu2[d];
            const int ks = eswz(kw + w + PF + d);      // prefetch PF ahead
            bu1[d] = tU1[ks]; bol[d] = tOL[ks]; bu2[d] = tU2[ks];
            const float r1 = rcpa(1.0f + exp2a(fmaf(c, M1, A1)));
            const float r2 = rcpa(1.0f + exp2a(fmaf(c, M2, A2)));
            const float s  = fmaf(oo1, r1, oogw1 * r2);    // oo + oogw
            const float lc = fminf(olv * c, u2);           // olc * c
            c = fmaf(-s, c, (c + u1) - lc);
        }
    }

    // ---- emit CHUNK steps into LDS ----
    const int ke = i * CHUNK + WARM;
#pragma unroll
    for (int j = 0; j < CHUNK; ++j) {
        const int ks = eswz(ke + j);
        const float u1 = tU1[ks], olv = tOL[ks], u2 = tU2[ks];
        const float oo   = oo1   * rcpa(1.0f + exp2a(fmaf(c, M1, A1)));
        const float oogw = oogw1 * rcpa(1.0f + exp2a(fmaf(c, M2, A2)));
        const float lc   = fminf(olv * c, u2);             // olc * c
        const float qq   = u2 * rcpa(c);
        const float olc  = (c > 0.0f) ? fminf(olv, qq) : olv;
        const float f    = 1.0f - oo - oogw - olc;
        const int eb_ = i * CHUNK + j;
        obuf[eswz(0 * SPAN + eb_)] = oo * c;     // h
        obuf[eswz(1 * SPAN + eb_)] = c;          // c
        obuf[eswz(2 * SPAN + eb_)] = olv * c;    // l
        obuf[eswz(3 * SPAN + eb_)] = lc;         // lc
        obuf[eswz(4 * SPAN + eb_)] = oogw * c;   // gw
        obuf[eswz(5 * SPAN + eb_)] = oo;         // g_oo
        obuf[eswz(6 * SPAN + eb_)] = olv;        // g_ol
        obuf[eswz(7 * SPAN + eb_)] = olc;        // g_olc
        obuf[eswz(8 * SPAN + eb_)] = f;          // g_f
        obuf[eswz(9 * SPAN + eb_)] = oogw;       // g_oogw
        c = fmaf(-(oo + oogw), c, (c + u1) - lc);
    }
    __syncthreads();

    // ---- coalesced flush ----
    const size_t Bs = (size_t)B;
    float* o_h    = out;
    float* o_c    = out + 1 * Bs;
    float* o_l    = out + 2 * Bs;
    float* o_lc   = out + 3 * Bs;
    float* o_gw   = out + 5 * Bs;
    float* o_goo  = out + 7 * Bs;
    float* o_gol  = out + 8 * Bs;
    float* o_golc = out + 9 * Bs;
    float* o_gf   = out + 10 * Bs;
    float* o_gogw = out + 11 * Bs;
    float* o_hno  = out + 12 * Bs;
#pragma unroll
    for (int n = 0; n < SPAN / BLK; ++n) {
        const int e = n * BLK + threadIdx.x;
        const int g = blkbase + e;
        if (g < N) {
            const int b = tl + g;
            const float h = obuf[eswz(0 * SPAN + e)];
            o_h[b]    = h;
            o_hno[2 * (size_t)b] = h;
            o_c[b]    = obuf[eswz(1 * SPAN + e)];
            o_l[b]    = obuf[eswz(2 * SPAN + e)];
            o_lc[b]   = obuf[eswz(3 * SPAN + e)];
            o_gw[b]   = obuf[eswz(4 * SPAN + e)];
            o_goo[b]  = obuf[eswz(5 * SPAN + e)];
            o_gol[b]  = obuf[eswz(6 * SPAN + e)];
            o_golc[b] = obuf[eswz(7 * SPAN + e)];
            o_gf[b]   = obuf[eswz(8 * SPAN + e)];
            o_gogw[b] = obuf[eswz(9 * SPAN + e)];
        }
    }
}

extern "C" void kernel_launch(void* const* d_in, const int* in_sizes, int n_in,
                              void* d_out, int out_size, void* d_ws, size_t ws_size,
                              hipStream_t stream) {
    const float* x          = (const float*)d_in[0];
    const float* y_obs      = (const float*)d_in[1];
    const float* p_mean     = (const float*)d_in[2];
    const float* p_std      = (const float*)d_in[3];
    const float* w_r_yom    = (const float*)d_in[4];
    const float* w_r_yom_gw = (const float*)d_in[5];
    const float* w_r_ylm    = (const float*)d_in[6];
    const float* w_r_yfm    = (const float*)d_in[7];
    const float* b0_yom     = (const float*)d_in[8];
    const float* w_b1_yom   = (const float*)d_in[9];
    const float* b0_yom_gw  = (const float*)d_in[10];
    const float* w_b1_yomgw = (const float*)d_in[11];
    const float* b0_ylm     = (const float*)d_in[12];
    const float* w_b2_ylm   = (const float*)d_in[13];
    // d_in[14] = epoch (unused)
    const int*   tlp        = (const int*)d_in[15];

    float* out = (float*)d_out;
    const int B = in_sizes[1];

    hipLaunchKernelGGL(fill_kernel, dim3((B + 255) / 256), dim3(256), 0, stream,
                       y_obs, out, B, tlp);

    const int nchunks = (B + CHUNK - 1) / CHUNK;
    const int nblocks = (nchunks + BLK - 1) / BLK;
    hipLaunchKernelGGL(scan_kernel, dim3(nblocks), dim3(BLK), 0, stream,
                       x, p_mean, p_std, w_r_yom, w_r_yom_gw, w_r_ylm, w_r_yfm,
                       b0_yom, w_b1_yom, b0_yom_gw, w_b1_yomgw, b0_ylm, w_b2_ylm,
                       tlp, out, B);
}